// Round 1
// baseline (810.971 us; speedup 1.0000x reference)
//
#include <hip/hip_runtime.h>
#include <math.h>

#define N 512
#define NN (N*N)
#define D 128
#define DD (D*D)
#define ND (N*D)
#define LSTR 132   // LDS row stride (floats) for 128-wide tiles
#define CSTR 68    // LDS row stride for 64-wide c tile
#define GRID 288

__device__ __forceinline__ float sigmoidf_(float x) { return 1.f / (1.f + expf(-x)); }

// Device-scope grid barrier. Safe because all GRID blocks are co-resident:
// LDS 63488 B -> 2 blocks/CU, 256 CUs -> capacity 512 >= 288.
__device__ __forceinline__ void gsync(unsigned* cnt, int bar) {
    __threadfence();                 // release: flush this block's writes to device scope
    __syncthreads();
    if (threadIdx.x == 0) {
        atomicAdd(&cnt[bar], 1u);
        while (__hip_atomic_load(&cnt[bar], __ATOMIC_ACQUIRE, __HIP_MEMORY_SCOPE_AGENT) < (unsigned)GRID) {
            __builtin_amdgcn_s_sleep(8);
        }
    }
    __syncthreads();
    __threadfence();                 // acquire: invalidate stale L1/L2 lines before reads
}

__global__ __launch_bounds__(256, 2) void k_fused(
    const float* __restrict__ seq, const float* __restrict__ W_mem,
    const float* __restrict__ W_q, const float* __restrict__ W_kv,
    const float* __restrict__ W_mom, const float* __restrict__ W_step,
    const float* __restrict__ W_decay, float* __restrict__ out, void* ws)
{
    __shared__ __align__(16) float smem[15872];   // 63488 B, re-carved per phase
    const int bid = blockIdx.x;
    const int tid = threadIdx.x;

    unsigned* cnt = (unsigned*)ws;                // 16 slots, memset to 0 per launch
    float* base  = (float*)ws + 64;
    float* am    = base;                          // N
    float* dec   = am + N;                        // N
    float* Q     = dec + N;                       // N*D
    float* INS   = Q + ND;                        // 4*N*D
    float* ES    = INS + 4 * ND;                  // 4*N*D
    float* betaP = ES + 4 * ND;                   // 2*N*N (split-2 slabs)
    float* WT    = betaP + 2 * NN;                // 3*D*D
    float* Pa    = WT + 3 * DD;                   // 9*N*D
    float* Pb    = Pa + 9 * ND;                   // 9*N*D
    double* LA   = (double*)(Pb + 9 * ND);        // N
    double* LDp  = LA + N;                        // N
    int* NC      = (int*)(LDp + N);               // N

    // ================= P0: W transpose (idle blocks) || P1 forward =================
    if (bid >= 256) {
        // blocks 256..287 transpose W_mem layers 1..3 -> WT, overlapped with phase1 fwd
        int b0 = (bid - 256) * 1536;
        #pragma unroll
        for (int q = 0; q < 6; q++) {
            int idx = b0 + q * 256 + tid;
            int l = idx / DD, rr = idx % DD;
            int i = rr / D, j = rr % D;
            WT[idx] = W_mem[(l + 1) * DD + j * D + i];
        }
    } else {
        // 2 tokens per block: h = token half, j = feature
        const int h = tid >> 7, j = tid & 127;
        const int t = bid * 2 + h;
        float* s_seq = smem;            // [2][128]
        float* s_v   = smem + 256;      // [2][128]
        float* s_cur = smem + 512;      // [2][128]
        float* s_h   = smem + 768;      // [4][2][128]
        float* s_red = smem + 1792;     // [4 waves][3]
        float* s_lr  = smem + 1804;     // [2]
        float x = seq[t * D + j];
        s_seq[h * 128 + j] = x;
        float p0 = x * W_step[j], p1 = x * W_mom[j], p2 = x * W_decay[j];
        #pragma unroll
        for (int off = 32; off > 0; off >>= 1) {
            p0 += __shfl_down(p0, off);
            p1 += __shfl_down(p1, off);
            p2 += __shfl_down(p2, off);
        }
        if ((tid & 63) == 0) {
            int w = tid >> 6;
            s_red[w * 3] = p0; s_red[w * 3 + 1] = p1; s_red[w * 3 + 2] = p2;
        }
        __syncthreads();
        if (tid < 2) {
            s_lr[tid] = s_red[(2 * tid) * 3] + s_red[(2 * tid + 1) * 3];
            am[bid * 2 + tid] = s_red[(2 * tid) * 3 + 1] + s_red[(2 * tid + 1) * 3 + 1];
            dec[bid * 2 + tid] = 1.f - sigmoidf_(s_red[(2 * tid) * 3 + 2] + s_red[(2 * tid + 1) * 3 + 2]);
        }
        // k / v / q full-depth dots (3 independent accumulator chains)
        float kp = 0.f, vp = 0.f, qp = 0.f;
        #pragma unroll 4
        for (int i = 0; i < D; i++) {
            float si = s_seq[h * 128 + i];
            kp += si * W_kv[i * 256 + j];
            vp += si * W_kv[i * 256 + 128 + j];
            qp += si * W_q[i * 128 + j];
        }
        s_cur[h * 128 + j] = kp;
        INS[t * D + j] = kp;
        s_v[h * 128 + j] = vp;
        Q[t * D + j] = qp;
        __syncthreads();
        // 4 forward layers
        for (int l = 0; l < 4; l++) {
            const float* Wl = W_mem + l * DD;
            float y0 = 0.f, y1 = 0.f;
            #pragma unroll 4
            for (int i = 0; i < D; i += 2) {
                y0 += s_cur[h * 128 + i]     * Wl[i * D + j];
                y1 += s_cur[h * 128 + i + 1] * Wl[(i + 1) * D + j];
            }
            float y = y0 + y1;
            __syncthreads();
            s_h[l * 256 + h * 128 + j] = y;
            if (l < 3) {
                float a = y * sigmoidf_(y);
                s_cur[h * 128 + j] = a;
                INS[(l + 1) * ND + t * D + j] = a;
            }
            __syncthreads();
        }
    }

    gsync(cnt, 0);   // publishes WT, am, dec (LDS h/v/lr state persists per block)

    // ================= P1 backward (0..255) || log-scan (256) =================
    if (bid < 256) {
        const int h = tid >> 7, j = tid & 127;
        const int t = bid * 2 + h;
        float* s_v   = smem + 256;
        float* s_cur = smem + 512;
        float* s_h   = smem + 768;
        float* s_lr  = smem + 1804;
        float e = -s_lr[h] * (2.f / (float)D) * (s_h[3 * 256 + h * 128 + j] - s_v[h * 128 + j]);
        ES[3 * ND + t * D + j] = e;
        s_cur[h * 128 + j] = e;
        __syncthreads();
        for (int l = 3; l >= 1; l--) {
            const float* Wt = WT + (l - 1) * DD;
            float g0 = 0.f, g1 = 0.f;
            #pragma unroll 4
            for (int i = 0; i < D; i += 2) {
                g0 += s_cur[h * 128 + i]     * Wt[i * D + j];
                g1 += s_cur[h * 128 + i + 1] * Wt[(i + 1) * D + j];
            }
            float g = g0 + g1;
            float hh = s_h[(l - 1) * 256 + h * 128 + j];
            float sg = sigmoidf_(hh);
            float e2 = g * (sg * (1.f + hh * (1.f - sg)));
            ES[(l - 1) * ND + t * D + j] = e2;
            __syncthreads();
            s_cur[h * 128 + j] = e2;
            __syncthreads();
        }
    } else if (bid == 256) {
        // 512-wide double-precision Hillis-Steele scan, 2 elems/thread
        double* sa = (double*)smem;
        double* sd = sa + 512;
        int* sn = (int*)(sd + 512);
        for (int k = tid; k < N; k += 256) {
            float a = am[k], d = dec[k];
            sa[k] = log((double)fmaxf(fabsf(a), 1e-38f));
            sd[k] = log((double)fmaxf(d, 1e-38f));
            sn[k] = (a < 0.f) ? 1 : 0;
        }
        __syncthreads();
        for (int off = 1; off < N; off <<= 1) {
            int k0 = tid, k1 = tid + 256;
            double va0 = 0., vd0 = 0., va1 = 0., vd1 = 0.;
            int vn0 = 0, vn1 = 0;
            if (k0 >= off) { va0 = sa[k0 - off]; vd0 = sd[k0 - off]; vn0 = sn[k0 - off]; }
            if (k1 >= off) { va1 = sa[k1 - off]; vd1 = sd[k1 - off]; vn1 = sn[k1 - off]; }
            __syncthreads();
            sa[k0] += va0; sd[k0] += vd0; sn[k0] += vn0;
            sa[k1] += va1; sd[k1] += vd1; sn[k1] += vn1;
            __syncthreads();
        }
        for (int k = tid; k < N; k += 256) { LA[k] = sa[k]; LDp[k] = sd[k]; NC[k] = sn[k]; }
    }

    gsync(cnt, 1);   // publishes ES, INS, Q, LA/LDp/NC

    // ========== P2: betamm, split-2, A/D tiles exp'd on the fly (k_build fused) ==========
    if (bid < 272) {
        int pid = bid >> 1, zz = bid & 1;
        int bt = 0;
        while (pid >= bt + 1) { pid -= bt + 1; bt++; }
        int bs = pid;
        const int span = bt - bs + 1;
        const int chunk = (span + 1) >> 1;
        const int kBeg = bs + zz * chunk;
        const int kEnd = (kBeg + chunk < bt + 1) ? (kBeg + chunk) : (bt + 1);

        float* sA  = smem;                        // [32][34]
        float* sDT = smem + 1088;                 // [32][34] transposed
        double* lA = (double*)(smem + 2176);      // 512
        double* lD = lA + 512;                    // 512
        int* nC    = (int*)(lD + 512);            // 512
        for (int k = tid; k < N; k += 256) { lA[k] = LA[k]; lD[k] = LDp[k]; nC[k] = NC[k]; }
        __syncthreads();

        const int tx = tid & 15, ty = tid >> 4;
        float acc00 = 0.f, acc01 = 0.f, acc10 = 0.f, acc11 = 0.f;
        for (int kt = kBeg; kt < kEnd; kt++) {
            for (int i = tid; i < 1024; i += 256) {
                int rr = i >> 5, c = i & 31;
                int u = kt * 32 + rr, s2 = bs * 32 + c;
                float va = 0.f;
                if (s2 <= u) {
                    va = expf((float)(lA[u] - lA[s2]));
                    if ((nC[u] - nC[s2]) & 1) va = -va;
                }
                sA[rr * 34 + c] = va;
                int tt = bt * 32 + rr, kk = kt * 32 + c;
                float vd = 0.f;
                if (kk <= tt) vd = expf((float)(lD[tt] - lD[kk]));
                sDT[c * 34 + rr] = vd;
            }
            __syncthreads();
            #pragma unroll 8
            for (int k = 0; k < 32; k++) {
                float2 a = *(float2*)&sA[k * 34 + 2 * tx];
                float2 d = *(float2*)&sDT[k * 34 + 2 * ty];
                acc00 += d.x * a.x; acc01 += d.x * a.y;
                acc10 += d.y * a.x; acc11 += d.y * a.y;
            }
            __syncthreads();
        }
        // always write (empty ranges write zeros -> slab1 of diagonal pairs is valid)
        float* bp = betaP + zz * NN + (bt * 32 + 2 * ty) * N + bs * 32 + 2 * tx;
        *(float2*)bp       = make_float2(acc00, acc01);
        *(float2*)(bp + N) = make_float2(acc10, acc11);
    } else if (bid < 280) {
        // zero the strictly-upper tiles (2q, 2q+1) that layers read, in both slabs
        int q = bid - 272;
        for (int i = tid; i < 1024; i += 256) {
            int rr = i >> 5, c = i & 31;
            int off = (q * 64 + rr) * N + q * 64 + 32 + c;
            betaP[off] = 0.f;
            betaP[NN + off] = 0.f;
        }
    }

    gsync(cnt, 2);   // publishes betaP

    // ================= 4 layers, grid barrier between =================
    const int r = bid & 31, z = bid >> 5;
    const int t0 = r * 16;
    for (int l = 0; l < 4; l++) {
        const float* Xsrc = (l == 0) ? Q : ((l & 1) ? Pa : Pb);
        float* Pout = (l & 1) ? Pb : Pa;
        const float* Wl   = W_mem + l * DD;
        const float* INSl = INS + l * ND;
        const float* ESl  = ES + l * ND;
        const int mode = (l > 0);
        const bool isW = (z == 8);
        if (isW || 4 * z <= r) {
            float* sX = smem;            // 16*132
            float* sI = smem + 2112;     // 64*132
            float* sE = smem + 10560;    // 32*132
            float* sc = smem + 14784;    // 16*68
            const int nzs = (r >> 2) + 1;
            #pragma unroll
            for (int i2 = 0; i2 < 2; i2++) {
                int f4 = tid + 256 * i2;
                int row = f4 >> 5, c4 = f4 & 31;
                float4 v = ((const float4*)(Xsrc + t0 * D))[f4];
                if (mode) {
                    for (int zp = 1; zp < nzs; zp++) {
                        float4 u = ((const float4*)(Xsrc + zp * ND + t0 * D))[f4];
                        v.x += u.x; v.y += u.y; v.z += u.z; v.w += u.w;
                    }
                    float4 w = ((const float4*)(Xsrc + 8 * ND + t0 * D))[f4];
                    v.x += w.x; v.y += w.y; v.z += w.z; v.w += w.w;
                    v.x = v.x * sigmoidf_(v.x); v.y = v.y * sigmoidf_(v.y);
                    v.z = v.z * sigmoidf_(v.z); v.w = v.w * sigmoidf_(v.w);
                }
                *(float4*)(sX + row * LSTR + c4 * 4) = v;
            }
            if (isW) {
                __syncthreads();
                const int ti = tid >> 4, j8 = (tid & 15) * 8;
                float a0=0.f,a1=0.f,a2=0.f,a3=0.f,a4=0.f,a5=0.f,a6=0.f,a7=0.f;
                #pragma unroll 4
                for (int k = 0; k < D; k++) {
                    float4 w0 = *(const float4*)(Wl + k * D + j8);
                    float4 w1 = *(const float4*)(Wl + k * D + j8 + 4);
                    float xv = sX[ti * LSTR + k];
                    a0 += xv * w0.x; a1 += xv * w0.y; a2 += xv * w0.z; a3 += xv * w0.w;
                    a4 += xv * w1.x; a5 += xv * w1.y; a6 += xv * w1.z; a7 += xv * w1.w;
                }
                float* yp = Pout + 8 * ND + (t0 + ti) * D + j8;
                *(float4*)yp       = make_float4(a0, a1, a2, a3);
                *(float4*)(yp + 4) = make_float4(a4, a5, a6, a7);
                // gsync's __syncthreads protects sX against next layer's restage
            } else {
                const int s0 = z * 64;
                #pragma unroll
                for (int i2 = 0; i2 < 8; i2++) {
                    int f4 = tid + 256 * i2;
                    int row = f4 >> 5, c4 = f4 & 31;
                    float4 a = ((const float4*)(INSl + s0 * D))[f4];
                    *(float4*)(sI + row * LSTR + c4 * 4) = a;
                }
                const int rp = tid >> 5, sp = tid & 31;
                int ib = (t0 + 2 * rp) * N + s0 + sp;
                float b00 = betaP[ib]          + betaP[NN + ib];
                float b01 = betaP[ib + 32]     + betaP[NN + ib + 32];
                float b10 = betaP[ib + N]      + betaP[NN + ib + N];
                float b11 = betaP[ib + N + 32] + betaP[NN + ib + N + 32];
                __syncthreads();
                float g00 = 0.f, g01 = 0.f, g10 = 0.f, g11 = 0.f;
                #pragma unroll 8
                for (int k4 = 0; k4 < D; k4 += 4) {
                    float4 x0 = *(float4*)(sX + (2 * rp) * LSTR + k4);
                    float4 x1 = *(float4*)(sX + (2 * rp + 1) * LSTR + k4);
                    float4 p0 = *(float4*)(sI + sp * LSTR + k4);
                    float4 p1 = *(float4*)(sI + (sp + 32) * LSTR + k4);
                    g00 += x0.x*p0.x + x0.y*p0.y + x0.z*p0.z + x0.w*p0.w;
                    g01 += x0.x*p1.x + x0.y*p1.y + x0.z*p1.z + x0.w*p1.w;
                    g10 += x1.x*p0.x + x1.y*p0.y + x1.z*p0.z + x1.w*p0.w;
                    g11 += x1.x*p1.x + x1.y*p1.y + x1.z*p1.z + x1.w*p1.w;
                }
                sc[(2 * rp) * CSTR + sp]          = g00 * b00;
                sc[(2 * rp) * CSTR + sp + 32]     = g01 * b01;
                sc[(2 * rp + 1) * CSTR + sp]      = g10 * b10;
                sc[(2 * rp + 1) * CSTR + sp + 32] = g11 * b11;
                const int tp = tid >> 5, jc = (tid & 31) * 4;
                float c00=0.f,c01=0.f,c02=0.f,c03=0.f,c10=0.f,c11=0.f,c12=0.f,c13=0.f;
                for (int sub = 0; sub < 2; sub++) {
                    __syncthreads();   // sc ready (sub 0) / prior sE reads done (sub 1)
                    #pragma unroll
                    for (int i2 = 0; i2 < 4; i2++) {
                        int f4 = tid + 256 * i2;
                        int row = f4 >> 5, c4 = f4 & 31;
                        float4 b = ((const float4*)(ESl + (s0 + sub * 32) * D))[f4];
                        *(float4*)(sE + row * LSTR + c4 * 4) = b;
                    }
                    __syncthreads();
                    const float* scp0 = sc + tp * CSTR + sub * 32;
                    const float* scp1 = sc + (tp + 8) * CSTR + sub * 32;
                    #pragma unroll 8
                    for (int s = 0; s < 32; s++) {
                        float v0 = scp0[s], v1 = scp1[s];
                        float4 e = *(float4*)(sE + s * LSTR + jc);
                        c00 += v0 * e.x; c01 += v0 * e.y; c02 += v0 * e.z; c03 += v0 * e.w;
                        c10 += v1 * e.x; c11 += v1 * e.y; c12 += v1 * e.z; c13 += v1 * e.w;
                    }
                }
                float* yp0 = Pout + z * ND + (t0 + tp) * D + jc;
                float* yp1 = Pout + z * ND + (t0 + tp + 8) * D + jc;
                *(float4*)yp0 = make_float4(c00, c01, c02, c03);
                *(float4*)yp1 = make_float4(c10, c11, c12, c13);
            }
        }
        gsync(cnt, 3 + l);
    }

    // ================= final reduce =================
    if (bid < 64) {
        int f4 = bid * 256 + tid;
        int t = f4 >> 5;
        int rr = t >> 4;
        int nzs = (rr >> 2) + 1;
        float4 v = ((const float4*)Pb)[f4];
        for (int zp = 1; zp < nzs; zp++) {
            float4 u = ((const float4*)(Pb + zp * ND))[f4];
            v.x += u.x; v.y += u.y; v.z += u.z; v.w += u.w;
        }
        float4 w = ((const float4*)(Pb + 8 * ND))[f4];
        v.x += w.x; v.y += w.y; v.z += w.z; v.w += w.w;
        ((float4*)out)[f4] = v;
    }
}

extern "C" void kernel_launch(void* const* d_in, const int* in_sizes, int n_in,
                              void* d_out, int out_size, void* d_ws, size_t ws_size,
                              hipStream_t stream) {
    // zero the 16 barrier counters (captured as a graph memset node)
    hipMemsetAsync(d_ws, 0, 64, stream);
    hipLaunchKernelGGL(k_fused, dim3(GRID), dim3(256), 0, stream,
        (const float*)d_in[0], (const float*)d_in[1], (const float*)d_in[2],
        (const float*)d_in[3], (const float*)d_in[4], (const float*)d_in[5],
        (const float*)d_in[6], (float*)d_out, d_ws);
}

// Round 2
// 276.884 us; speedup vs baseline: 2.9289x; 2.9289x over previous
//
#include <hip/hip_runtime.h>
#include <math.h>

#define N 512
#define NN (N*N)
#define D 128
#define DD (D*D)
#define ND (N*D)
#define LSTR 132   // LDS row stride (floats) for 128-wide tiles
#define CSTR 68    // LDS row stride for 64-wide c tile
#define GRID 288

__device__ __forceinline__ float sigmoidf_(float x) { return 1.f / (1.f + expf(-x)); }

// Device-scope grid barrier. Safe because all GRID blocks are co-resident:
// LDS 63488 B -> 2 blocks/CU, 256 CUs -> capacity 512 >= 288.
// Protocol: release-RMW on arrival (one wbl2/block), RELAXED spin (sc1 load to
// coherence point, NO per-poll cache invalidate), single acquire fence on exit.
// R1's bug: acquire-per-poll emitted an L2-wide buffer_inv every ~512 cycles
// per spinner -> memory system DoS (756us @ 1.2% VALUBusy).
__device__ __forceinline__ void gsync(unsigned* cnt, int bar) {
    __syncthreads();   // drains vmcnt: all waves' stores are in L2 (L1 is write-through)
    if (threadIdx.x == 0) {
        __hip_atomic_fetch_add(&cnt[bar], 1u, __ATOMIC_RELEASE, __HIP_MEMORY_SCOPE_AGENT);
        while (__hip_atomic_load(&cnt[bar], __ATOMIC_RELAXED, __HIP_MEMORY_SCOPE_AGENT) < (unsigned)GRID) {
            __builtin_amdgcn_s_sleep(32);   // ~2048 cy between polls; keeps LLC slice cool
        }
        __builtin_amdgcn_fence(__ATOMIC_ACQUIRE, "agent");  // one L1/L2 inv per block
    }
    __syncthreads();
}

__global__ __launch_bounds__(256, 2) void k_fused(
    const float* __restrict__ seq, const float* __restrict__ W_mem,
    const float* __restrict__ W_q, const float* __restrict__ W_kv,
    const float* __restrict__ W_mom, const float* __restrict__ W_step,
    const float* __restrict__ W_decay, float* __restrict__ out, void* ws)
{
    __shared__ __align__(16) float smem[15872];   // 63488 B, re-carved per phase
    const int bid = blockIdx.x;
    const int tid = threadIdx.x;

    unsigned* cnt = (unsigned*)ws;                // 16 slots, memset to 0 per launch
    float* base  = (float*)ws + 64;
    float* am    = base;                          // N
    float* dec   = am + N;                        // N
    float* Q     = dec + N;                       // N*D
    float* INS   = Q + ND;                        // 4*N*D
    float* ES    = INS + 4 * ND;                  // 4*N*D
    float* betaP = ES + 4 * ND;                   // 2*N*N (split-2 slabs)
    float* WT    = betaP + 2 * NN;                // 3*D*D
    float* Pa    = WT + 3 * DD;                   // 9*N*D
    float* Pb    = Pa + 9 * ND;                   // 9*N*D
    double* LA   = (double*)(Pb + 9 * ND);        // N
    double* LDp  = LA + N;                        // N
    int* NC      = (int*)(LDp + N);               // N

    // ================= P0: W transpose (idle blocks) || P1 forward =================
    if (bid >= 256) {
        // blocks 256..287 transpose W_mem layers 1..3 -> WT, overlapped with phase1 fwd
        int b0 = (bid - 256) * 1536;
        #pragma unroll
        for (int q = 0; q < 6; q++) {
            int idx = b0 + q * 256 + tid;
            int l = idx / DD, rr = idx % DD;
            int i = rr / D, j = rr % D;
            WT[idx] = W_mem[(l + 1) * DD + j * D + i];
        }
    } else {
        // 2 tokens per block: h = token half, j = feature
        const int h = tid >> 7, j = tid & 127;
        const int t = bid * 2 + h;
        float* s_seq = smem;            // [2][128]
        float* s_v   = smem + 256;      // [2][128]
        float* s_cur = smem + 512;      // [2][128]
        float* s_h   = smem + 768;      // [4][2][128]
        float* s_red = smem + 1792;     // [4 waves][3]
        float* s_lr  = smem + 1804;     // [2]
        float x = seq[t * D + j];
        s_seq[h * 128 + j] = x;
        float p0 = x * W_step[j], p1 = x * W_mom[j], p2 = x * W_decay[j];
        #pragma unroll
        for (int off = 32; off > 0; off >>= 1) {
            p0 += __shfl_down(p0, off);
            p1 += __shfl_down(p1, off);
            p2 += __shfl_down(p2, off);
        }
        if ((tid & 63) == 0) {
            int w = tid >> 6;
            s_red[w * 3] = p0; s_red[w * 3 + 1] = p1; s_red[w * 3 + 2] = p2;
        }
        __syncthreads();
        if (tid < 2) {
            s_lr[tid] = s_red[(2 * tid) * 3] + s_red[(2 * tid + 1) * 3];
            am[bid * 2 + tid] = s_red[(2 * tid) * 3 + 1] + s_red[(2 * tid + 1) * 3 + 1];
            dec[bid * 2 + tid] = 1.f - sigmoidf_(s_red[(2 * tid) * 3 + 2] + s_red[(2 * tid + 1) * 3 + 2]);
        }
        // k / v / q full-depth dots (3 independent accumulator chains)
        float kp = 0.f, vp = 0.f, qp = 0.f;
        #pragma unroll 4
        for (int i = 0; i < D; i++) {
            float si = s_seq[h * 128 + i];
            kp += si * W_kv[i * 256 + j];
            vp += si * W_kv[i * 256 + 128 + j];
            qp += si * W_q[i * 128 + j];
        }
        s_cur[h * 128 + j] = kp;
        INS[t * D + j] = kp;
        s_v[h * 128 + j] = vp;
        Q[t * D + j] = qp;
        __syncthreads();
        // 4 forward layers
        for (int l = 0; l < 4; l++) {
            const float* Wl = W_mem + l * DD;
            float y0 = 0.f, y1 = 0.f;
            #pragma unroll 4
            for (int i = 0; i < D; i += 2) {
                y0 += s_cur[h * 128 + i]     * Wl[i * D + j];
                y1 += s_cur[h * 128 + i + 1] * Wl[(i + 1) * D + j];
            }
            float y = y0 + y1;
            __syncthreads();
            s_h[l * 256 + h * 128 + j] = y;
            if (l < 3) {
                float a = y * sigmoidf_(y);
                s_cur[h * 128 + j] = a;
                INS[(l + 1) * ND + t * D + j] = a;
            }
            __syncthreads();
        }
    }

    gsync(cnt, 0);   // publishes WT, am, dec (LDS h/v/lr state persists per block)

    // ================= P1 backward (0..255) || log-scan (256) =================
    if (bid < 256) {
        const int h = tid >> 7, j = tid & 127;
        const int t = bid * 2 + h;
        float* s_v   = smem + 256;
        float* s_cur = smem + 512;
        float* s_h   = smem + 768;
        float* s_lr  = smem + 1804;
        float e = -s_lr[h] * (2.f / (float)D) * (s_h[3 * 256 + h * 128 + j] - s_v[h * 128 + j]);
        ES[3 * ND + t * D + j] = e;
        s_cur[h * 128 + j] = e;
        __syncthreads();
        for (int l = 3; l >= 1; l--) {
            const float* Wt = WT + (l - 1) * DD;
            float g0 = 0.f, g1 = 0.f;
            #pragma unroll 4
            for (int i = 0; i < D; i += 2) {
                g0 += s_cur[h * 128 + i]     * Wt[i * D + j];
                g1 += s_cur[h * 128 + i + 1] * Wt[(i + 1) * D + j];
            }
            float g = g0 + g1;
            float hh = s_h[(l - 1) * 256 + h * 128 + j];
            float sg = sigmoidf_(hh);
            float e2 = g * (sg * (1.f + hh * (1.f - sg)));
            ES[(l - 1) * ND + t * D + j] = e2;
            __syncthreads();
            s_cur[h * 128 + j] = e2;
            __syncthreads();
        }
    } else if (bid == 256) {
        // 512-wide double-precision Hillis-Steele scan, 2 elems/thread
        double* sa = (double*)smem;
        double* sd = sa + 512;
        int* sn = (int*)(sd + 512);
        for (int k = tid; k < N; k += 256) {
            float a = am[k], d = dec[k];
            sa[k] = log((double)fmaxf(fabsf(a), 1e-38f));
            sd[k] = log((double)fmaxf(d, 1e-38f));
            sn[k] = (a < 0.f) ? 1 : 0;
        }
        __syncthreads();
        for (int off = 1; off < N; off <<= 1) {
            int k0 = tid, k1 = tid + 256;
            double va0 = 0., vd0 = 0., va1 = 0., vd1 = 0.;
            int vn0 = 0, vn1 = 0;
            if (k0 >= off) { va0 = sa[k0 - off]; vd0 = sd[k0 - off]; vn0 = sn[k0 - off]; }
            if (k1 >= off) { va1 = sa[k1 - off]; vd1 = sd[k1 - off]; vn1 = sn[k1 - off]; }
            __syncthreads();
            sa[k0] += va0; sd[k0] += vd0; sn[k0] += vn0;
            sa[k1] += va1; sd[k1] += vd1; sn[k1] += vn1;
            __syncthreads();
        }
        for (int k = tid; k < N; k += 256) { LA[k] = sa[k]; LDp[k] = sd[k]; NC[k] = sn[k]; }
    }

    gsync(cnt, 1);   // publishes ES, INS, Q, LA/LDp/NC

    // ========== P2: betamm, split-2, A/D tiles exp'd on the fly (k_build fused) ==========
    if (bid < 272) {
        int pid = bid >> 1, zz = bid & 1;
        int bt = 0;
        while (pid >= bt + 1) { pid -= bt + 1; bt++; }
        int bs = pid;
        const int span = bt - bs + 1;
        const int chunk = (span + 1) >> 1;
        const int kBeg = bs + zz * chunk;
        const int kEnd = (kBeg + chunk < bt + 1) ? (kBeg + chunk) : (bt + 1);

        float* sA  = smem;                        // [32][34]
        float* sDT = smem + 1088;                 // [32][34] transposed
        double* lA = (double*)(smem + 2176);      // 512
        double* lD = lA + 512;                    // 512
        int* nC    = (int*)(lD + 512);            // 512
        for (int k = tid; k < N; k += 256) { lA[k] = LA[k]; lD[k] = LDp[k]; nC[k] = NC[k]; }
        __syncthreads();

        const int tx = tid & 15, ty = tid >> 4;
        float acc00 = 0.f, acc01 = 0.f, acc10 = 0.f, acc11 = 0.f;
        for (int kt = kBeg; kt < kEnd; kt++) {
            for (int i = tid; i < 1024; i += 256) {
                int rr = i >> 5, c = i & 31;
                int u = kt * 32 + rr, s2 = bs * 32 + c;
                float va = 0.f;
                if (s2 <= u) {
                    va = expf((float)(lA[u] - lA[s2]));
                    if ((nC[u] - nC[s2]) & 1) va = -va;
                }
                sA[rr * 34 + c] = va;
                int tt = bt * 32 + rr, kk = kt * 32 + c;
                float vd = 0.f;
                if (kk <= tt) vd = expf((float)(lD[tt] - lD[kk]));
                sDT[c * 34 + rr] = vd;
            }
            __syncthreads();
            #pragma unroll 8
            for (int k = 0; k < 32; k++) {
                float2 a = *(float2*)&sA[k * 34 + 2 * tx];
                float2 d = *(float2*)&sDT[k * 34 + 2 * ty];
                acc00 += d.x * a.x; acc01 += d.x * a.y;
                acc10 += d.y * a.x; acc11 += d.y * a.y;
            }
            __syncthreads();
        }
        // always write (empty ranges write zeros -> slab1 of diagonal pairs is valid)
        float* bp = betaP + zz * NN + (bt * 32 + 2 * ty) * N + bs * 32 + 2 * tx;
        *(float2*)bp       = make_float2(acc00, acc01);
        *(float2*)(bp + N) = make_float2(acc10, acc11);
    } else if (bid < 280) {
        // zero the strictly-upper tiles (2q, 2q+1) that layers read, in both slabs
        int q = bid - 272;
        for (int i = tid; i < 1024; i += 256) {
            int rr = i >> 5, c = i & 31;
            int off = (q * 64 + rr) * N + q * 64 + 32 + c;
            betaP[off] = 0.f;
            betaP[NN + off] = 0.f;
        }
    }

    gsync(cnt, 2);   // publishes betaP

    // ================= 4 layers, grid barrier between =================
    const int r = bid & 31, z = bid >> 5;
    const int t0 = r * 16;
    for (int l = 0; l < 4; l++) {
        const float* Xsrc = (l == 0) ? Q : ((l & 1) ? Pa : Pb);
        float* Pout = (l & 1) ? Pb : Pa;
        const float* Wl   = W_mem + l * DD;
        const float* INSl = INS + l * ND;
        const float* ESl  = ES + l * ND;
        const int mode = (l > 0);
        const bool isW = (z == 8);
        if (isW || 4 * z <= r) {
            float* sX = smem;            // 16*132
            float* sI = smem + 2112;     // 64*132
            float* sE = smem + 10560;    // 32*132
            float* sc = smem + 14784;    // 16*68
            const int nzs = (r >> 2) + 1;
            #pragma unroll
            for (int i2 = 0; i2 < 2; i2++) {
                int f4 = tid + 256 * i2;
                int row = f4 >> 5, c4 = f4 & 31;
                float4 v = ((const float4*)(Xsrc + t0 * D))[f4];
                if (mode) {
                    for (int zp = 1; zp < nzs; zp++) {
                        float4 u = ((const float4*)(Xsrc + zp * ND + t0 * D))[f4];
                        v.x += u.x; v.y += u.y; v.z += u.z; v.w += u.w;
                    }
                    float4 w = ((const float4*)(Xsrc + 8 * ND + t0 * D))[f4];
                    v.x += w.x; v.y += w.y; v.z += w.z; v.w += w.w;
                    v.x = v.x * sigmoidf_(v.x); v.y = v.y * sigmoidf_(v.y);
                    v.z = v.z * sigmoidf_(v.z); v.w = v.w * sigmoidf_(v.w);
                }
                *(float4*)(sX + row * LSTR + c4 * 4) = v;
            }
            if (isW) {
                __syncthreads();
                const int ti = tid >> 4, j8 = (tid & 15) * 8;
                float a0=0.f,a1=0.f,a2=0.f,a3=0.f,a4=0.f,a5=0.f,a6=0.f,a7=0.f;
                #pragma unroll 4
                for (int k = 0; k < D; k++) {
                    float4 w0 = *(const float4*)(Wl + k * D + j8);
                    float4 w1 = *(const float4*)(Wl + k * D + j8 + 4);
                    float xv = sX[ti * LSTR + k];
                    a0 += xv * w0.x; a1 += xv * w0.y; a2 += xv * w0.z; a3 += xv * w0.w;
                    a4 += xv * w1.x; a5 += xv * w1.y; a6 += xv * w1.z; a7 += xv * w1.w;
                }
                float* yp = Pout + 8 * ND + (t0 + ti) * D + j8;
                *(float4*)yp       = make_float4(a0, a1, a2, a3);
                *(float4*)(yp + 4) = make_float4(a4, a5, a6, a7);
                // gsync's __syncthreads protects sX against next layer's restage
            } else {
                const int s0 = z * 64;
                #pragma unroll
                for (int i2 = 0; i2 < 8; i2++) {
                    int f4 = tid + 256 * i2;
                    int row = f4 >> 5, c4 = f4 & 31;
                    float4 a = ((const float4*)(INSl + s0 * D))[f4];
                    *(float4*)(sI + row * LSTR + c4 * 4) = a;
                }
                const int rp = tid >> 5, sp = tid & 31;
                int ib = (t0 + 2 * rp) * N + s0 + sp;
                float b00 = betaP[ib]          + betaP[NN + ib];
                float b01 = betaP[ib + 32]     + betaP[NN + ib + 32];
                float b10 = betaP[ib + N]      + betaP[NN + ib + N];
                float b11 = betaP[ib + N + 32] + betaP[NN + ib + N + 32];
                __syncthreads();
                float g00 = 0.f, g01 = 0.f, g10 = 0.f, g11 = 0.f;
                #pragma unroll 8
                for (int k4 = 0; k4 < D; k4 += 4) {
                    float4 x0 = *(float4*)(sX + (2 * rp) * LSTR + k4);
                    float4 x1 = *(float4*)(sX + (2 * rp + 1) * LSTR + k4);
                    float4 p0 = *(float4*)(sI + sp * LSTR + k4);
                    float4 p1 = *(float4*)(sI + (sp + 32) * LSTR + k4);
                    g00 += x0.x*p0.x + x0.y*p0.y + x0.z*p0.z + x0.w*p0.w;
                    g01 += x0.x*p1.x + x0.y*p1.y + x0.z*p1.z + x0.w*p1.w;
                    g10 += x1.x*p0.x + x1.y*p0.y + x1.z*p0.z + x1.w*p0.w;
                    g11 += x1.x*p1.x + x1.y*p1.y + x1.z*p1.z + x1.w*p1.w;
                }
                sc[(2 * rp) * CSTR + sp]          = g00 * b00;
                sc[(2 * rp) * CSTR + sp + 32]     = g01 * b01;
                sc[(2 * rp + 1) * CSTR + sp]      = g10 * b10;
                sc[(2 * rp + 1) * CSTR + sp + 32] = g11 * b11;
                const int tp = tid >> 5, jc = (tid & 31) * 4;
                float c00=0.f,c01=0.f,c02=0.f,c03=0.f,c10=0.f,c11=0.f,c12=0.f,c13=0.f;
                for (int sub = 0; sub < 2; sub++) {
                    __syncthreads();   // sc ready (sub 0) / prior sE reads done (sub 1)
                    #pragma unroll
                    for (int i2 = 0; i2 < 4; i2++) {
                        int f4 = tid + 256 * i2;
                        int row = f4 >> 5, c4 = f4 & 31;
                        float4 b = ((const float4*)(ESl + (s0 + sub * 32) * D))[f4];
                        *(float4*)(sE + row * LSTR + c4 * 4) = b;
                    }
                    __syncthreads();
                    const float* scp0 = sc + tp * CSTR + sub * 32;
                    const float* scp1 = sc + (tp + 8) * CSTR + sub * 32;
                    #pragma unroll 8
                    for (int s = 0; s < 32; s++) {
                        float v0 = scp0[s], v1 = scp1[s];
                        float4 e = *(float4*)(sE + s * LSTR + jc);
                        c00 += v0 * e.x; c01 += v0 * e.y; c02 += v0 * e.z; c03 += v0 * e.w;
                        c10 += v1 * e.x; c11 += v1 * e.y; c12 += v1 * e.z; c13 += v1 * e.w;
                    }
                }
                float* yp0 = Pout + z * ND + (t0 + tp) * D + jc;
                float* yp1 = Pout + z * ND + (t0 + tp + 8) * D + jc;
                *(float4*)yp0 = make_float4(c00, c01, c02, c03);
                *(float4*)yp1 = make_float4(c10, c11, c12, c13);
            }
        }
        gsync(cnt, 3 + l);
    }

    // ================= final reduce =================
    if (bid < 64) {
        int f4 = bid * 256 + tid;
        int t = f4 >> 5;
        int rr = t >> 4;
        int nzs = (rr >> 2) + 1;
        float4 v = ((const float4*)Pb)[f4];
        for (int zp = 1; zp < nzs; zp++) {
            float4 u = ((const float4*)(Pb + zp * ND))[f4];
            v.x += u.x; v.y += u.y; v.z += u.z; v.w += u.w;
        }
        float4 w = ((const float4*)(Pb + 8 * ND))[f4];
        v.x += w.x; v.y += w.y; v.z += w.z; v.w += w.w;
        ((float4*)out)[f4] = v;
    }
}

extern "C" void kernel_launch(void* const* d_in, const int* in_sizes, int n_in,
                              void* d_out, int out_size, void* d_ws, size_t ws_size,
                              hipStream_t stream) {
    // zero the 16 barrier counters (captured as a graph memset node)
    hipMemsetAsync(d_ws, 0, 64, stream);
    hipLaunchKernelGGL(k_fused, dim3(GRID), dim3(256), 0, stream,
        (const float*)d_in[0], (const float*)d_in[1], (const float*)d_in[2],
        (const float*)d_in[3], (const float*)d_in[4], (const float*)d_in[5],
        (const float*)d_in[6], (float*)d_out, d_ws);
}

// Round 6
// 275.110 us; speedup vs baseline: 2.9478x; 1.0064x over previous
//
#include <hip/hip_runtime.h>
#include <math.h>

#define N 512
#define NN (N*N)
#define D 128
#define DD (D*D)
#define ND (N*D)
#define LSTR 132   // LDS row stride (floats) for 128-wide tiles
#define CSTR 68    // LDS row stride for 64-wide c tile
#define GRID 288
#define NFLUSH 32  // blocks 0..31 issue the per-XCD L2 writeback (round-robin dispatch
                   // -> covers all 8 XCDs with 4x redundancy)

typedef unsigned long long u64;

__device__ __forceinline__ float sigmoidf_(float x) { return 1.f / (1.f + expf(-x)); }

// ---- coherence-point loads for cross-block intermediates.
// Agent-scope relaxed atomic loads: the compiler emits the correct cache-bypass
// bits so the load observes the latest agent-visible value (LLC). Immune to
// stale L1/L2 lines -> NO acquire/invalidate is needed anywhere in the kernel.
// (R4 lesson: plain loads can hit stale lines pulled in by adjacent-address
// streaming; word-level single-assignment != line-level freshness.)
__device__ __forceinline__ float ld_f(const float* p) {
    unsigned u = __hip_atomic_load((const unsigned*)p, __ATOMIC_RELAXED, __HIP_MEMORY_SCOPE_AGENT);
    union { unsigned u; float f; } c; c.u = u; return c.f;
}
__device__ __forceinline__ float2 ld_f2(const float* p) {
    u64 u = __hip_atomic_load((const u64*)p, __ATOMIC_RELAXED, __HIP_MEMORY_SCOPE_AGENT);
    union { u64 u; float2 f; } c; c.u = u; return c.f;
}
__device__ __forceinline__ float4 ld_f4(const float* p) {   // p must be 8B-aligned
    float2 a = ld_f2(p), b = ld_f2(p + 2);
    return make_float4(a.x, a.y, b.x, b.y);
}
__device__ __forceinline__ double ld_d(const double* p) {
    u64 u = __hip_atomic_load((const u64*)p, __ATOMIC_RELAXED, __HIP_MEMORY_SCOPE_AGENT);
    union { u64 u; double d; } c; c.u = u; return c.d;
}
__device__ __forceinline__ int ld_i(const int* p) {
    return (int)__hip_atomic_load((const unsigned*)p, __ATOMIC_RELAXED, __HIP_MEMORY_SCOPE_AGENT);
}

// Device-scope grid barrier with minimal cache maintenance.
// R1: acquire-per-poll inv storm (756us). R2: per-block release-RMW + acquire
// fence = 288 wbl2 + 288 inv per barrier, correct but ~25us/barrier (216us).
// R4/R5: fence-free attempts failed -> sc0sc1 stores do NOT write through; the
// only reliable bulk release on gfx950 is buffer_wbl2.
// This protocol: plain stores stay dirty in the writer's XCD L2.
//   Phase A: all 288 blocks arrive (after __syncthreads' vmcnt(0) drain, every
//            block's stores are committed to its XCD L2).
//   Phase B: blocks 0..31 issue fence(release,agent) -> buffer_wbl2 sc1 (whole-
//            L2 writeback, covers ALL blocks on that XCD) + waitcnt, then count;
//            others count immediately. cntB==GRID => all 8 XCD L2s flushed =>
//            LLC fresh => ld_* reads are correct. 32 L2 ops/barrier, not 576.
__device__ __forceinline__ void gsync(unsigned* cnt, int bar, bool flusher) {
    __syncthreads();   // s_waitcnt vmcnt(0) before s_barrier: stores acked in local L2
    if (threadIdx.x == 0) {
        unsigned* a = cnt + 2 * bar;
        unsigned* b = a + 1;
        __hip_atomic_fetch_add(a, 1u, __ATOMIC_RELAXED, __HIP_MEMORY_SCOPE_AGENT);
        while (__hip_atomic_load(a, __ATOMIC_RELAXED, __HIP_MEMORY_SCOPE_AGENT) < (unsigned)GRID)
            __builtin_amdgcn_s_sleep(8);
        if (flusher) {
            __builtin_amdgcn_fence(__ATOMIC_RELEASE, "agent");  // s_waitcnt + buffer_wbl2 sc1
            __builtin_amdgcn_s_waitcnt(0);                      // wbl2 completion (vmcnt-tracked)
        }
        __hip_atomic_fetch_add(b, 1u, __ATOMIC_RELAXED, __HIP_MEMORY_SCOPE_AGENT);
        while (__hip_atomic_load(b, __ATOMIC_RELAXED, __HIP_MEMORY_SCOPE_AGENT) < (unsigned)GRID)
            __builtin_amdgcn_s_sleep(8);
    }
    __syncthreads();
}

__global__ __launch_bounds__(256, 2) void k_fused(
    const float* __restrict__ seq, const float* __restrict__ W_mem,
    const float* __restrict__ W_q, const float* __restrict__ W_kv,
    const float* __restrict__ W_mom, const float* __restrict__ W_step,
    const float* __restrict__ W_decay, float* __restrict__ out, void* ws)
{
    __shared__ __align__(16) float smem[15872];   // 63488 B, re-carved per phase
    const int bid = blockIdx.x;
    const int tid = threadIdx.x;
    const bool flusher = (bid < NFLUSH);

    unsigned* cnt = (unsigned*)ws;                // 16 slots (14 used), memset 0 per launch
    float* base  = (float*)ws + 64;
    float* am    = base;                          // N
    float* dec   = am + N;                        // N
    float* Q     = dec + N;                       // N*D
    float* INS   = Q + ND;                        // 4*N*D
    float* ES    = INS + 4 * ND;                  // 4*N*D
    float* betaP = ES + 4 * ND;                   // 2*N*N (split-2 slabs)
    float* Pbase = betaP + 2 * NN;                // 4 * 9*N*D (single-assignment per layer)
    double* LA   = (double*)(Pbase + 36 * ND);    // N
    double* LDp  = LA + N;                        // N
    int* NC      = (int*)(LDp + N);               // N

    // ================= P0: phase-1 forward (blocks 0..255) =================
    if (bid < 256) {
        // 2 tokens per block: h = token half, j = feature
        const int h = tid >> 7, j = tid & 127;
        const int t = bid * 2 + h;
        float* s_seq = smem;            // [2][128]
        float* s_v   = smem + 256;      // [2][128]
        float* s_cur = smem + 512;      // [2][128]
        float* s_h   = smem + 768;      // [4][2][128]
        float* s_red = smem + 1792;     // [4 waves][3]
        float* s_lr  = smem + 1804;     // [2]
        float x = seq[t * D + j];
        s_seq[h * 128 + j] = x;
        float p0 = x * W_step[j], p1 = x * W_mom[j], p2 = x * W_decay[j];
        #pragma unroll
        for (int off = 32; off > 0; off >>= 1) {
            p0 += __shfl_down(p0, off);
            p1 += __shfl_down(p1, off);
            p2 += __shfl_down(p2, off);
        }
        if ((tid & 63) == 0) {
            int w = tid >> 6;
            s_red[w * 3] = p0; s_red[w * 3 + 1] = p1; s_red[w * 3 + 2] = p2;
        }
        __syncthreads();
        if (tid < 2) {
            s_lr[tid] = s_red[(2 * tid) * 3] + s_red[(2 * tid + 1) * 3];
            am[bid * 2 + tid] = s_red[(2 * tid) * 3 + 1] + s_red[(2 * tid + 1) * 3 + 1];
            dec[bid * 2 + tid] = 1.f - sigmoidf_(s_red[(2 * tid) * 3 + 2] + s_red[(2 * tid + 1) * 3 + 2]);
        }
        // k / v / q full-depth dots (3 independent accumulator chains)
        float kp = 0.f, vp = 0.f, qp = 0.f;
        #pragma unroll 4
        for (int i = 0; i < D; i++) {
            float si = s_seq[h * 128 + i];
            kp += si * W_kv[i * 256 + j];
            vp += si * W_kv[i * 256 + 128 + j];
            qp += si * W_q[i * 128 + j];
        }
        s_cur[h * 128 + j] = kp;
        INS[t * D + j] = kp;
        s_v[h * 128 + j] = vp;
        Q[t * D + j] = qp;
        __syncthreads();
        // 4 forward layers
        for (int l = 0; l < 4; l++) {
            const float* Wl = W_mem + l * DD;
            float y0 = 0.f, y1 = 0.f;
            #pragma unroll 4
            for (int i = 0; i < D; i += 2) {
                y0 += s_cur[h * 128 + i]     * Wl[i * D + j];
                y1 += s_cur[h * 128 + i + 1] * Wl[(i + 1) * D + j];
            }
            float y = y0 + y1;
            __syncthreads();
            s_h[l * 256 + h * 128 + j] = y;
            if (l < 3) {
                float a = y * sigmoidf_(y);
                s_cur[h * 128 + j] = a;
                INS[(l + 1) * ND + t * D + j] = a;
            }
            __syncthreads();
        }
    }
    // blocks 256..287 idle in P0 (WT transpose eliminated: backward reads W rows)

    gsync(cnt, 0, flusher);   // publishes am, dec (LDS h/v/lr state persists per block)

    // ================= P1 backward (0..255) || log-scan (256) =================
    if (bid < 256) {
        const int h = tid >> 7, j = tid & 127;
        const int t = bid * 2 + h;
        float* s_v   = smem + 256;
        float* s_cur = smem + 512;
        float* s_h   = smem + 768;
        float* s_lr  = smem + 1804;
        float e = -s_lr[h] * (2.f / (float)D) * (s_h[3 * 256 + h * 128 + j] - s_v[h * 128 + j]);
        ES[3 * ND + t * D + j] = e;
        s_cur[h * 128 + j] = e;
        __syncthreads();
        for (int l = 3; l >= 1; l--) {
            // g_j = sum_i cur_i * W[l][j][i] : thread j walks ROW j of W_mem layer l
            // (contiguous 512B per thread; read-only input -> plain cached loads)
            const float* Wrow = W_mem + l * DD + j * D;
            float g0 = 0.f, g1 = 0.f;
            #pragma unroll 8
            for (int i4 = 0; i4 < D; i4 += 4) {
                float4 w = *(const float4*)(Wrow + i4);
                g0 += s_cur[h * 128 + i4]     * w.x + s_cur[h * 128 + i4 + 1] * w.y;
                g1 += s_cur[h * 128 + i4 + 2] * w.z + s_cur[h * 128 + i4 + 3] * w.w;
            }
            float g = g0 + g1;
            float hh = s_h[(l - 1) * 256 + h * 128 + j];
            float sg = sigmoidf_(hh);
            float e2 = g * (sg * (1.f + hh * (1.f - sg)));
            ES[(l - 1) * ND + t * D + j] = e2;
            __syncthreads();
            s_cur[h * 128 + j] = e2;
            __syncthreads();
        }
    } else if (bid == 256) {
        // 512-wide double-precision Hillis-Steele scan, 2 elems/thread
        double* sa = (double*)smem;
        double* sd = sa + 512;
        int* sn = (int*)(sd + 512);
        for (int k = tid; k < N; k += 256) {
            float a = ld_f(am + k), d = ld_f(dec + k);
            sa[k] = log((double)fmaxf(fabsf(a), 1e-38f));
            sd[k] = log((double)fmaxf(d, 1e-38f));
            sn[k] = (a < 0.f) ? 1 : 0;
        }
        __syncthreads();
        for (int off = 1; off < N; off <<= 1) {
            int k0 = tid, k1 = tid + 256;
            double va0 = 0., vd0 = 0., va1 = 0., vd1 = 0.;
            int vn0 = 0, vn1 = 0;
            if (k0 >= off) { va0 = sa[k0 - off]; vd0 = sd[k0 - off]; vn0 = sn[k0 - off]; }
            if (k1 >= off) { va1 = sa[k1 - off]; vd1 = sd[k1 - off]; vn1 = sn[k1 - off]; }
            __syncthreads();
            sa[k0] += va0; sd[k0] += vd0; sn[k0] += vn0;
            sa[k1] += va1; sd[k1] += vd1; sn[k1] += vn1;
            __syncthreads();
        }
        for (int k = tid; k < N; k += 256) {
            LA[k] = sa[k]; LDp[k] = sd[k]; NC[k] = sn[k];
        }
    }

    gsync(cnt, 1, flusher);   // publishes ES, INS, Q, LA/LDp/NC

    // ========== P2: betamm, split-2, A/D tiles exp'd on the fly ==========
    if (bid < 272) {
        int pid = bid >> 1, zz = bid & 1;
        int bt = 0;
        while (pid >= bt + 1) { pid -= bt + 1; bt++; }
        int bs = pid;
        const int span = bt - bs + 1;
        const int chunk = (span + 1) >> 1;
        const int kBeg = bs + zz * chunk;
        const int kEnd = (kBeg + chunk < bt + 1) ? (kBeg + chunk) : (bt + 1);

        float* sA  = smem;                        // [32][34]
        float* sDT = smem + 1088;                 // [32][34] transposed
        double* lA = (double*)(smem + 2176);      // 512
        double* lD = lA + 512;                    // 512
        int* nC    = (int*)(lD + 512);            // 512
        for (int k = tid; k < N; k += 256) {
            lA[k] = ld_d(LA + k); lD[k] = ld_d(LDp + k); nC[k] = ld_i(NC + k);
        }
        __syncthreads();

        const int tx = tid & 15, ty = tid >> 4;
        float acc00 = 0.f, acc01 = 0.f, acc10 = 0.f, acc11 = 0.f;
        for (int kt = kBeg; kt < kEnd; kt++) {
            for (int i = tid; i < 1024; i += 256) {
                int rr = i >> 5, c = i & 31;
                int u = kt * 32 + rr, s2 = bs * 32 + c;
                float va = 0.f;
                if (s2 <= u) {
                    va = expf((float)(lA[u] - lA[s2]));
                    if ((nC[u] - nC[s2]) & 1) va = -va;
                }
                sA[rr * 34 + c] = va;
                int tt = bt * 32 + rr, kk = kt * 32 + c;
                float vd = 0.f;
                if (kk <= tt) vd = expf((float)(lD[tt] - lD[kk]));
                sDT[c * 34 + rr] = vd;
            }
            __syncthreads();
            #pragma unroll 8
            for (int k = 0; k < 32; k++) {
                float2 a = *(float2*)&sA[k * 34 + 2 * tx];
                float2 d = *(float2*)&sDT[k * 34 + 2 * ty];
                acc00 += d.x * a.x; acc01 += d.x * a.y;
                acc10 += d.y * a.x; acc11 += d.y * a.y;
            }
            __syncthreads();
        }
        // always write (empty ranges write zeros -> slab1 of diagonal pairs is valid)
        float* bp = betaP + zz * NN + (bt * 32 + 2 * ty) * N + bs * 32 + 2 * tx;
        *(float2*)bp       = make_float2(acc00, acc01);
        *(float2*)(bp + N) = make_float2(acc10, acc11);
    } else if (bid < 280) {
        // zero the strictly-upper tiles (2q, 2q+1) that layers read, in both slabs
        int q = bid - 272;
        for (int i = tid; i < 1024; i += 256) {
            int rr = i >> 5, c = i & 31;
            int off = (q * 64 + rr) * N + q * 64 + 32 + c;
            betaP[off] = 0.f;
            betaP[NN + off] = 0.f;
        }
    }

    gsync(cnt, 2, flusher);   // publishes betaP

    // ================= 4 layers, grid barrier between =================
    const int r = bid & 31, z = bid >> 5;
    const int t0 = r * 16;
    for (int l = 0; l < 4; l++) {
        // single-assignment P buffers: layer l writes Pbase+l*9ND, reads Pbase+(l-1)*9ND
        const float* Xsrc = (l == 0) ? Q : (Pbase + (l - 1) * 9 * ND);
        float* Pout = Pbase + l * 9 * ND;
        const float* Wl   = W_mem + l * DD;
        const float* INSl = INS + l * ND;
        const float* ESl  = ES + l * ND;
        const int mode = (l > 0);
        const bool isW = (z == 8);
        if (isW || 4 * z <= r) {
            float* sX = smem;            // 16*132
            float* sI = smem + 2112;     // 64*132
            float* sE = smem + 10560;    // 32*132
            float* sc = smem + 14784;    // 16*68
            const int nzs = (r >> 2) + 1;
            #pragma unroll
            for (int i2 = 0; i2 < 2; i2++) {
                int f4 = tid + 256 * i2;
                int row = f4 >> 5, c4 = f4 & 31;
                float4 v = ld_f4(Xsrc + t0 * D + 4 * f4);
                if (mode) {
                    for (int zp = 1; zp < nzs; zp++) {
                        float4 u = ld_f4(Xsrc + zp * ND + t0 * D + 4 * f4);
                        v.x += u.x; v.y += u.y; v.z += u.z; v.w += u.w;
                    }
                    float4 w = ld_f4(Xsrc + 8 * ND + t0 * D + 4 * f4);
                    v.x += w.x; v.y += w.y; v.z += w.z; v.w += w.w;
                    v.x = v.x * sigmoidf_(v.x); v.y = v.y * sigmoidf_(v.y);
                    v.z = v.z * sigmoidf_(v.z); v.w = v.w * sigmoidf_(v.w);
                }
                *(float4*)(sX + row * LSTR + c4 * 4) = v;
            }
            if (isW) {
                __syncthreads();
                const int ti = tid >> 4, j8 = (tid & 15) * 8;
                float a0=0.f,a1=0.f,a2=0.f,a3=0.f,a4=0.f,a5=0.f,a6=0.f,a7=0.f;
                #pragma unroll 4
                for (int k = 0; k < D; k++) {
                    float4 w0 = *(const float4*)(Wl + k * D + j8);
                    float4 w1 = *(const float4*)(Wl + k * D + j8 + 4);
                    float xv = sX[ti * LSTR + k];
                    a0 += xv * w0.x; a1 += xv * w0.y; a2 += xv * w0.z; a3 += xv * w0.w;
                    a4 += xv * w1.x; a5 += xv * w1.y; a6 += xv * w1.z; a7 += xv * w1.w;
                }
                float* yp = Pout + 8 * ND + (t0 + ti) * D + j8;
                *(float4*)yp       = make_float4(a0, a1, a2, a3);
                *(float4*)(yp + 4) = make_float4(a4, a5, a6, a7);
                // gsync's __syncthreads protects sX against next layer's restage
            } else {
                const int s0 = z * 64;
                #pragma unroll
                for (int i2 = 0; i2 < 8; i2++) {
                    int f4 = tid + 256 * i2;
                    int row = f4 >> 5, c4 = f4 & 31;
                    float4 a = ld_f4(INSl + s0 * D + 4 * f4);
                    *(float4*)(sI + row * LSTR + c4 * 4) = a;
                }
                const int rp = tid >> 5, sp = tid & 31;
                int ib = (t0 + 2 * rp) * N + s0 + sp;
                float b00 = ld_f(betaP + ib)          + ld_f(betaP + NN + ib);
                float b01 = ld_f(betaP + ib + 32)     + ld_f(betaP + NN + ib + 32);
                float b10 = ld_f(betaP + ib + N)      + ld_f(betaP + NN + ib + N);
                float b11 = ld_f(betaP + ib + N + 32) + ld_f(betaP + NN + ib + N + 32);
                __syncthreads();
                float g00 = 0.f, g01 = 0.f, g10 = 0.f, g11 = 0.f;
                #pragma unroll 8
                for (int k4 = 0; k4 < D; k4 += 4) {
                    float4 x0 = *(float4*)(sX + (2 * rp) * LSTR + k4);
                    float4 x1 = *(float4*)(sX + (2 * rp + 1) * LSTR + k4);
                    float4 p0 = *(float4*)(sI + sp * LSTR + k4);
                    float4 p1 = *(float4*)(sI + (sp + 32) * LSTR + k4);
                    g00 += x0.x*p0.x + x0.y*p0.y + x0.z*p0.z + x0.w*p0.w;
                    g01 += x0.x*p1.x + x0.y*p1.y + x0.z*p1.z + x0.w*p1.w;
                    g10 += x1.x*p0.x + x1.y*p0.y + x1.z*p0.z + x1.w*p0.w;
                    g11 += x1.x*p1.x + x1.y*p1.y + x1.z*p1.z + x1.w*p1.w;
                }
                sc[(2 * rp) * CSTR + sp]          = g00 * b00;
                sc[(2 * rp) * CSTR + sp + 32]     = g01 * b01;
                sc[(2 * rp + 1) * CSTR + sp]      = g10 * b10;
                sc[(2 * rp + 1) * CSTR + sp + 32] = g11 * b11;
                const int tp = tid >> 5, jc = (tid & 31) * 4;
                float c00=0.f,c01=0.f,c02=0.f,c03=0.f,c10=0.f,c11=0.f,c12=0.f,c13=0.f;
                for (int sub = 0; sub < 2; sub++) {
                    __syncthreads();   // sc ready (sub 0) / prior sE reads done (sub 1)
                    #pragma unroll
                    for (int i2 = 0; i2 < 4; i2++) {
                        int f4 = tid + 256 * i2;
                        int row = f4 >> 5, c4 = f4 & 31;
                        float4 b = ld_f4(ESl + (s0 + sub * 32) * D + 4 * f4);
                        *(float4*)(sE + row * LSTR + c4 * 4) = b;
                    }
                    __syncthreads();
                    const float* scp0 = sc + tp * CSTR + sub * 32;
                    const float* scp1 = sc + (tp + 8) * CSTR + sub * 32;
                    #pragma unroll 8
                    for (int s = 0; s < 32; s++) {
                        float v0 = scp0[s], v1 = scp1[s];
                        float4 e = *(float4*)(sE + s * LSTR + jc);
                        c00 += v0 * e.x; c01 += v0 * e.y; c02 += v0 * e.z; c03 += v0 * e.w;
                        c10 += v1 * e.x; c11 += v1 * e.y; c12 += v1 * e.z; c13 += v1 * e.w;
                    }
                }
                float* yp0 = Pout + z * ND + (t0 + tp) * D + jc;
                float* yp1 = Pout + z * ND + (t0 + tp + 8) * D + jc;
                *(float4*)yp0 = make_float4(c00, c01, c02, c03);
                *(float4*)yp1 = make_float4(c10, c11, c12, c13);
            }
        }
        gsync(cnt, 3 + l, flusher);
    }

    // ================= final reduce =================
    if (bid < 64) {
        const float* P3 = Pbase + 3 * 9 * ND;
        int f4 = bid * 256 + tid;
        int t = f4 >> 5;
        int rr = t >> 4;
        int nzs = (rr >> 2) + 1;
        float4 v = ld_f4(P3 + 4 * f4);
        for (int zp = 1; zp < nzs; zp++) {
            float4 u = ld_f4(P3 + zp * ND + 4 * f4);
            v.x += u.x; v.y += u.y; v.z += u.z; v.w += u.w;
        }
        float4 w = ld_f4(P3 + 8 * ND + 4 * f4);
        v.x += w.x; v.y += w.y; v.z += w.z; v.w += w.w;
        ((float4*)out)[f4] = v;   // host visibility: end-of-kernel implicit release
    }
}

extern "C" void kernel_launch(void* const* d_in, const int* in_sizes, int n_in,
                              void* d_out, int out_size, void* d_ws, size_t ws_size,
                              hipStream_t stream) {
    // zero the 16 barrier counters (captured as a graph memset node)
    (void)hipMemsetAsync(d_ws, 0, 64, stream);
    hipLaunchKernelGGL(k_fused, dim3(GRID), dim3(256), 0, stream,
        (const float*)d_in[0], (const float*)d_in[1], (const float*)d_in[2],
        (const float*)d_in[3], (const float*)d_in[4], (const float*)d_in[5],
        (const float*)d_in[6], (float*)d_out, d_ws);
}

// Round 7
// 210.143 us; speedup vs baseline: 3.8591x; 1.3092x over previous
//
#include <hip/hip_runtime.h>
#include <math.h>

#define N 512
#define NN (N*N)
#define D 128
#define DD (D*D)
#define ND (N*D)
#define LSTR 132   // LDS row stride (floats) for 128-wide tiles
#define CSTR 68    // LDS row stride for 64-wide c tile
#define GRID 288

typedef unsigned long long u64;
typedef unsigned uint32;

__device__ __forceinline__ float sigmoidf_(float x) { return 1.f / (1.f + expf(-x)); }

// ---- LLC-routed loads for cross-block intermediates (proven R6).
// Agent-scope relaxed atomic loads bypass stale L1/XCD-L2 lines and read the
// coherence point. Paired with plain stores + per-XCD wbl2 at the barrier.
__device__ __forceinline__ float ld_f(const float* p) {
    uint32 u = __hip_atomic_load((const uint32*)p, __ATOMIC_RELAXED, __HIP_MEMORY_SCOPE_AGENT);
    union { uint32 u; float f; } c; c.u = u; return c.f;
}
__device__ __forceinline__ float2 ld_f2(const float* p) {
    u64 u = __hip_atomic_load((const u64*)p, __ATOMIC_RELAXED, __HIP_MEMORY_SCOPE_AGENT);
    union { u64 u; float2 f; } c; c.u = u; return c.f;
}
__device__ __forceinline__ float4 ld_f4(const float* p) {   // p must be 8B-aligned
    float2 a = ld_f2(p), b = ld_f2(p + 2);
    return make_float4(a.x, a.y, b.x, b.y);
}

// Two-level tree grid barrier. R2 vs R6 proved barrier cost (~27us) is NOT
// cache-maintenance count (576 ops -> 32 ops: no change). Remaining suspect:
// 288 same-cacheline RMWs serializing as a dependency chain (~94ns each) +
// 288 same-line spinners. This tree caps any same-line RMW chain at 36:
//   arrive:  fetch_add grp[bid&7] (8 separate 64B lines)
//   promote: group-last adds 36 to root Rar
//   flush:   bid<32 wait Rar==288 (global arrival => all stores in their L2s),
//            fence(release,agent) = per-XCD buffer_wbl2, then count into Fc.
//            (bid 0..31 span all 8 XCDs under round-robin dispatch - R6-proven.)
//   release: bid0 waits Fc==32 (all L2s flushed => LLC fresh), stores 8 rel lines
//   spin:    each block polls its own group's rel line (36 spinners/line)
__device__ __forceinline__ void gsync(uint32* C, int bar, int bid) {
    __syncthreads();   // s_waitcnt vmcnt(0): this block's stores are in its L2
    if (threadIdx.x == 0) {
        uint32* Cb  = C + bar * 512;           // 2KB per barrier, zeroed per launch
        uint32* grp = Cb + (bid & 7) * 16;     // 64B-spaced arrival counters
        uint32* Rar = Cb + 128;                // root arrival
        uint32* Fc  = Cb + 144;                // flush-done count
        uint32* rel = Cb + 256 + (bid & 7) * 16;   // 64B-spaced release flags
        uint32 old = __hip_atomic_fetch_add(grp, 1u, __ATOMIC_RELAXED, __HIP_MEMORY_SCOPE_AGENT);
        if (old == 35u)
            __hip_atomic_fetch_add(Rar, 36u, __ATOMIC_RELAXED, __HIP_MEMORY_SCOPE_AGENT);
        if (bid < 32) {
            while (__hip_atomic_load(Rar, __ATOMIC_RELAXED, __HIP_MEMORY_SCOPE_AGENT) < (uint32)GRID)
                __builtin_amdgcn_s_sleep(2);
            __builtin_amdgcn_fence(__ATOMIC_RELEASE, "agent");  // buffer_wbl2 (own XCD)
            __builtin_amdgcn_s_waitcnt(0);                      // wbl2 completion
            __hip_atomic_fetch_add(Fc, 1u, __ATOMIC_RELAXED, __HIP_MEMORY_SCOPE_AGENT);
        }
        if (bid == 0) {
            while (__hip_atomic_load(Fc, __ATOMIC_RELAXED, __HIP_MEMORY_SCOPE_AGENT) < 32u)
                __builtin_amdgcn_s_sleep(2);
            #pragma unroll
            for (int g2 = 0; g2 < 8; g2++)
                __hip_atomic_store(Cb + 256 + g2 * 16, 1u, __ATOMIC_RELAXED, __HIP_MEMORY_SCOPE_AGENT);
        }
        while (__hip_atomic_load(rel, __ATOMIC_RELAXED, __HIP_MEMORY_SCOPE_AGENT) == 0u)
            __builtin_amdgcn_s_sleep(2);
    }
    __syncthreads();
}

__global__ __launch_bounds__(256, 2) void k_fused(
    const float* __restrict__ seq, const float* __restrict__ W_mem,
    const float* __restrict__ W_q, const float* __restrict__ W_kv,
    const float* __restrict__ W_mom, const float* __restrict__ W_step,
    const float* __restrict__ W_decay, float* __restrict__ out, void* ws)
{
    __shared__ __align__(16) float smem[15872];   // 63488 B, re-carved per phase
    const int bid = blockIdx.x;
    const int tid = threadIdx.x;

    uint32* C    = (uint32*)ws;                   // 5 barriers x 2KB, memset 0
    float* base  = (float*)ws + 4096;
    float* Q     = base;                          // N*D
    float* INS   = Q + ND;                        // 4*N*D
    float* ES    = INS + 4 * ND;                  // 4*N*D
    float* betaP = ES + 4 * ND;                   // 2*N*N (split-2 slabs)
    float* Pbase = betaP + 2 * NN;                // 4 * 9*N*D (single-assignment per layer)

    // =========== PHASE A (no internal grid barrier): token fwd+bwd || scan || betamm ===========
    if (bid < 256) {
        // ---- token work: 2 tokens per block (h = token half, j = feature) ----
        const int h = tid >> 7, j = tid & 127;
        const int t = bid * 2 + h;
        float* s_seq = smem;            // [2][128]
        float* s_v   = smem + 256;      // [2][128]
        float* s_cur = smem + 512;      // [2][128]
        float* s_h   = smem + 768;      // [4][2][128]
        float* s_red = smem + 1792;     // [4 waves]
        float* s_lr  = smem + 1800;     // [2]
        float x = seq[t * D + j];
        s_seq[h * 128 + j] = x;
        float p0 = x * W_step[j];
        #pragma unroll
        for (int off = 32; off > 0; off >>= 1) p0 += __shfl_down(p0, off);
        if ((tid & 63) == 0) s_red[tid >> 6] = p0;
        __syncthreads();
        if (tid < 2) s_lr[tid] = s_red[2 * tid] + s_red[2 * tid + 1];
        // k / v / q full-depth dots
        float kp = 0.f, vp = 0.f, qp = 0.f;
        #pragma unroll 4
        for (int i = 0; i < D; i++) {
            float si = s_seq[h * 128 + i];
            kp += si * W_kv[i * 256 + j];
            vp += si * W_kv[i * 256 + 128 + j];
            qp += si * W_q[i * 128 + j];
        }
        s_cur[h * 128 + j] = kp;
        INS[t * D + j] = kp;
        s_v[h * 128 + j] = vp;
        Q[t * D + j] = qp;
        __syncthreads();
        // 4 forward layers
        for (int l = 0; l < 4; l++) {
            const float* Wl = W_mem + l * DD;
            float y0 = 0.f, y1 = 0.f;
            #pragma unroll 4
            for (int i = 0; i < D; i += 2) {
                y0 += s_cur[h * 128 + i]     * Wl[i * D + j];
                y1 += s_cur[h * 128 + i + 1] * Wl[(i + 1) * D + j];
            }
            float y = y0 + y1;
            __syncthreads();
            s_h[l * 256 + h * 128 + j] = y;
            if (l < 3) {
                float a = y * sigmoidf_(y);
                s_cur[h * 128 + j] = a;
                INS[(l + 1) * ND + t * D + j] = a;
            }
            __syncthreads();
        }
        // ---- backward (W rows read directly; WT eliminated) ----
        float e = -s_lr[h] * (2.f / (float)D) * (s_h[3 * 256 + h * 128 + j] - s_v[h * 128 + j]);
        ES[3 * ND + t * D + j] = e;
        s_cur[h * 128 + j] = e;
        __syncthreads();
        for (int l = 3; l >= 1; l--) {
            const float* Wrow = W_mem + l * DD + j * D;
            float g0 = 0.f, g1 = 0.f;
            #pragma unroll 8
            for (int i4 = 0; i4 < D; i4 += 4) {
                float4 w = *(const float4*)(Wrow + i4);
                g0 += s_cur[h * 128 + i4]     * w.x + s_cur[h * 128 + i4 + 1] * w.y;
                g1 += s_cur[h * 128 + i4 + 2] * w.z + s_cur[h * 128 + i4 + 3] * w.w;
            }
            float g = g0 + g1;
            float hh = s_h[(l - 1) * 256 + h * 128 + j];
            float sg = sigmoidf_(hh);
            float e2 = g * (sg * (1.f + hh * (1.f - sg)));
            ES[(l - 1) * ND + t * D + j] = e2;
            __syncthreads();
            s_cur[h * 128 + j] = e2;
            __syncthreads();
        }
        __syncthreads();
    }

    // ---- local scan + betamm (blocks 0..271; heavy bt=15 tiles remapped to 256..271) ----
    if (bid < 272) {
        // every block computes the full 512-token log-scan itself (replaces 2 barriers)
        double* lA = (double*)smem;          // f[0..1023]
        double* lD = lA + 512;               // f[1024..2047]
        int*    nC = (int*)(lD + 512);       // f[2048..2559]
        float*  sA  = smem + 2560;           // [32][34]
        float*  sDT = smem + 3648;           // [32][34] transposed
        __syncthreads();                     // token-phase LDS dead
        #pragma unroll
        for (int h2 = 0; h2 < 2; h2++) {
            int t = tid + h2 * 256;
            const float* sp = seq + t * D;
            float aa = 0.f, dd = 0.f;
            #pragma unroll 8
            for (int i4 = 0; i4 < D; i4 += 4) {
                float4 s4 = *(const float4*)(sp + i4);
                float4 wm = *(const float4*)(W_mom + i4);
                float4 wd = *(const float4*)(W_decay + i4);
                aa += s4.x * wm.x + s4.y * wm.y + s4.z * wm.z + s4.w * wm.w;
                dd += s4.x * wd.x + s4.y * wd.y + s4.z * wd.z + s4.w * wd.w;
            }
            float d = 1.f - sigmoidf_(dd);
            lA[t] = log((double)fmaxf(fabsf(aa), 1e-38f));
            lD[t] = log((double)fmaxf(d, 1e-38f));
            nC[t] = (aa < 0.f) ? 1 : 0;
        }
        __syncthreads();
        for (int off = 1; off < N; off <<= 1) {
            int k0 = tid, k1 = tid + 256;
            double va0 = 0., vd0 = 0., va1 = 0., vd1 = 0.;
            int vn0 = 0, vn1 = 0;
            if (k0 >= off) { va0 = lA[k0 - off]; vd0 = lD[k0 - off]; vn0 = nC[k0 - off]; }
            if (k1 >= off) { va1 = lA[k1 - off]; vd1 = lD[k1 - off]; vn1 = nC[k1 - off]; }
            __syncthreads();
            lA[k0] += va0; lD[k0] += vd0; nC[k0] += vn0;
            lA[k1] += va1; lD[k1] += vd1; nC[k1] += vn1;
            __syncthreads();
        }

        // slot remap: idle-otherwise blocks 256..271 take the heavy bt=15,bs=0..7 tiles
        int slot = bid;
        if (bid >= 256) slot = bid - 16;
        else if (bid >= 240) slot = bid + 16;
        int pid = slot >> 1, zz = slot & 1;
        int bt = 0;
        while (pid >= bt + 1) { pid -= bt + 1; bt++; }
        int bs = pid;
        const int span = bt - bs + 1;
        const int chunk = (span + 1) >> 1;
        const int kBeg = bs + zz * chunk;
        const int kEnd = (kBeg + chunk < bt + 1) ? (kBeg + chunk) : (bt + 1);

        const int tx = tid & 15, ty = tid >> 4;
        float acc00 = 0.f, acc01 = 0.f, acc10 = 0.f, acc11 = 0.f;
        for (int kt = kBeg; kt < kEnd; kt++) {
            for (int i = tid; i < 1024; i += 256) {
                int rr = i >> 5, c = i & 31;
                int u = kt * 32 + rr, s2 = bs * 32 + c;
                float va = 0.f;
                if (s2 <= u) {
                    va = expf((float)(lA[u] - lA[s2]));
                    if ((nC[u] - nC[s2]) & 1) va = -va;
                }
                sA[rr * 34 + c] = va;
                int tt = bt * 32 + rr, kk = kt * 32 + c;
                float vd = 0.f;
                if (kk <= tt) vd = expf((float)(lD[tt] - lD[kk]));
                sDT[c * 34 + rr] = vd;
            }
            __syncthreads();
            #pragma unroll 8
            for (int k = 0; k < 32; k++) {
                float2 a = *(float2*)&sA[k * 34 + 2 * tx];
                float2 d = *(float2*)&sDT[k * 34 + 2 * ty];
                acc00 += d.x * a.x; acc01 += d.x * a.y;
                acc10 += d.y * a.x; acc11 += d.y * a.y;
            }
            __syncthreads();
        }
        // always write (empty k-ranges write zeros -> slab1 of small-span tiles valid)
        float* bp = betaP + zz * NN + (bt * 32 + 2 * ty) * N + bs * 32 + 2 * tx;
        *(float2*)bp       = make_float2(acc00, acc01);
        *(float2*)(bp + N) = make_float2(acc10, acc11);
    }

    gsync(C, 0, bid);   // publishes Q, INS, ES, betaP

    // ================= 4 layers, tree barrier between =================
    const int r = bid & 31, z = bid >> 5;
    const int t0 = r * 16;
    for (int l = 0; l < 4; l++) {
        // single-assignment P buffers: layer l writes Pbase+l*9ND, reads Pbase+(l-1)*9ND
        const float* Xsrc = (l == 0) ? Q : (Pbase + (l - 1) * 9 * ND);
        float* Pout = Pbase + l * 9 * ND;
        const float* Wl   = W_mem + l * DD;
        const float* INSl = INS + l * ND;
        const float* ESl  = ES + l * ND;
        const int mode = (l > 0);
        const bool isW = (z == 8);
        if (isW || 4 * z <= r) {
            float* sX = smem;            // 16*132
            float* sI = smem + 2112;     // 64*132
            float* sE = smem + 10560;    // 32*132
            float* sc = smem + 14784;    // 16*68
            const int nzs = (r >> 2) + 1;
            #pragma unroll
            for (int i2 = 0; i2 < 2; i2++) {
                int f4 = tid + 256 * i2;
                int row = f4 >> 5, c4 = f4 & 31;
                float4 v = ld_f4(Xsrc + t0 * D + 4 * f4);
                if (mode) {
                    for (int zp = 1; zp < nzs; zp++) {
                        float4 u = ld_f4(Xsrc + zp * ND + t0 * D + 4 * f4);
                        v.x += u.x; v.y += u.y; v.z += u.z; v.w += u.w;
                    }
                    float4 w = ld_f4(Xsrc + 8 * ND + t0 * D + 4 * f4);
                    v.x += w.x; v.y += w.y; v.z += w.z; v.w += w.w;
                    v.x = v.x * sigmoidf_(v.x); v.y = v.y * sigmoidf_(v.y);
                    v.z = v.z * sigmoidf_(v.z); v.w = v.w * sigmoidf_(v.w);
                }
                *(float4*)(sX + row * LSTR + c4 * 4) = v;
            }
            if (isW) {
                __syncthreads();
                const int ti = tid >> 4, j8 = (tid & 15) * 8;
                float a0=0.f,a1=0.f,a2=0.f,a3=0.f,a4=0.f,a5=0.f,a6=0.f,a7=0.f;
                #pragma unroll 4
                for (int k = 0; k < D; k++) {
                    float4 w0 = *(const float4*)(Wl + k * D + j8);
                    float4 w1 = *(const float4*)(Wl + k * D + j8 + 4);
                    float xv = sX[ti * LSTR + k];
                    a0 += xv * w0.x; a1 += xv * w0.y; a2 += xv * w0.z; a3 += xv * w0.w;
                    a4 += xv * w1.x; a5 += xv * w1.y; a6 += xv * w1.z; a7 += xv * w1.w;
                }
                float* yp = Pout + 8 * ND + (t0 + ti) * D + j8;
                *(float4*)yp       = make_float4(a0, a1, a2, a3);
                *(float4*)(yp + 4) = make_float4(a4, a5, a6, a7);
            } else {
                const int s0 = z * 64;
                #pragma unroll
                for (int i2 = 0; i2 < 8; i2++) {
                    int f4 = tid + 256 * i2;
                    int row = f4 >> 5, c4 = f4 & 31;
                    float4 a = ld_f4(INSl + s0 * D + 4 * f4);
                    *(float4*)(sI + row * LSTR + c4 * 4) = a;
                }
                // beta prefetch with in-layer upper-triangle mask (replaces zeroing blocks;
                // strictly-upper 32-tiles are never written by betamm -> mask, don't trust)
                const int rp = tid >> 5, sp2 = tid & 31;
                const int row0 = t0 + 2 * rp, row1 = row0 + 1;
                const int col0 = s0 + sp2, col1 = col0 + 32;
                const int ib = row0 * N + col0;
                float b00 = (col0 <= row0) ? (ld_f(betaP + ib)          + ld_f(betaP + NN + ib))          : 0.f;
                float b01 = (col1 <= row0) ? (ld_f(betaP + ib + 32)     + ld_f(betaP + NN + ib + 32))     : 0.f;
                float b10 = (col0 <= row1) ? (ld_f(betaP + ib + N)      + ld_f(betaP + NN + ib + N))      : 0.f;
                float b11 = (col1 <= row1) ? (ld_f(betaP + ib + N + 32) + ld_f(betaP + NN + ib + N + 32)) : 0.f;
                __syncthreads();
                float g00 = 0.f, g01 = 0.f, g10 = 0.f, g11 = 0.f;
                #pragma unroll 8
                for (int k4 = 0; k4 < D; k4 += 4) {
                    float4 x0 = *(float4*)(sX + (2 * rp) * LSTR + k4);
                    float4 x1 = *(float4*)(sX + (2 * rp + 1) * LSTR + k4);
                    float4 p0 = *(float4*)(sI + sp2 * LSTR + k4);
                    float4 p1 = *(float4*)(sI + (sp2 + 32) * LSTR + k4);
                    g00 += x0.x*p0.x + x0.y*p0.y + x0.z*p0.z + x0.w*p0.w;
                    g01 += x0.x*p1.x + x0.y*p1.y + x0.z*p1.z + x0.w*p1.w;
                    g10 += x1.x*p0.x + x1.y*p0.y + x1.z*p0.z + x1.w*p0.w;
                    g11 += x1.x*p1.x + x1.y*p1.y + x1.z*p1.z + x1.w*p1.w;
                }
                sc[(2 * rp) * CSTR + sp2]          = g00 * b00;
                sc[(2 * rp) * CSTR + sp2 + 32]     = g01 * b01;
                sc[(2 * rp + 1) * CSTR + sp2]      = g10 * b10;
                sc[(2 * rp + 1) * CSTR + sp2 + 32] = g11 * b11;
                const int tp = tid >> 5, jc = (tid & 31) * 4;
                float c00=0.f,c01=0.f,c02=0.f,c03=0.f,c10=0.f,c11=0.f,c12=0.f,c13=0.f;
                for (int sub = 0; sub < 2; sub++) {
                    __syncthreads();   // sc ready (sub 0) / prior sE reads done (sub 1)
                    #pragma unroll
                    for (int i2 = 0; i2 < 4; i2++) {
                        int f4 = tid + 256 * i2;
                        int row = f4 >> 5, c4 = f4 & 31;
                        float4 b = ld_f4(ESl + (s0 + sub * 32) * D + 4 * f4);
                        *(float4*)(sE + row * LSTR + c4 * 4) = b;
                    }
                    __syncthreads();
                    const float* scp0 = sc + tp * CSTR + sub * 32;
                    const float* scp1 = sc + (tp + 8) * CSTR + sub * 32;
                    #pragma unroll 8
                    for (int s = 0; s < 32; s++) {
                        float v0 = scp0[s], v1 = scp1[s];
                        float4 e = *(float4*)(sE + s * LSTR + jc);
                        c00 += v0 * e.x; c01 += v0 * e.y; c02 += v0 * e.z; c03 += v0 * e.w;
                        c10 += v1 * e.x; c11 += v1 * e.y; c12 += v1 * e.z; c13 += v1 * e.w;
                    }
                }
                float* yp0 = Pout + z * ND + (t0 + tp) * D + jc;
                float* yp1 = Pout + z * ND + (t0 + tp + 8) * D + jc;
                *(float4*)yp0 = make_float4(c00, c01, c02, c03);
                *(float4*)yp1 = make_float4(c10, c11, c12, c13);
            }
        }
        gsync(C, 1 + l, bid);
    }

    // ================= final reduce =================
    if (bid < 64) {
        const float* P3 = Pbase + 3 * 9 * ND;
        int f4 = bid * 256 + tid;
        int t = f4 >> 5;
        int rr = t >> 4;
        int nzs = (rr >> 2) + 1;
        float4 v = ld_f4(P3 + 4 * f4);
        for (int zp = 1; zp < nzs; zp++) {
            float4 u = ld_f4(P3 + zp * ND + 4 * f4);
            v.x += u.x; v.y += u.y; v.z += u.z; v.w += u.w;
        }
        float4 w = ld_f4(P3 + 8 * ND + 4 * f4);
        v.x += w.x; v.y += w.y; v.z += w.z; v.w += w.w;
        ((float4*)out)[f4] = v;   // host visibility: end-of-kernel implicit release
    }
}

extern "C" void kernel_launch(void* const* d_in, const int* in_sizes, int n_in,
                              void* d_out, int out_size, void* d_ws, size_t ws_size,
                              hipStream_t stream) {
    // zero the 5 x 2KB tree-barrier counter region (graph memset node)
    (void)hipMemsetAsync(d_ws, 0, 10240, stream);
    hipLaunchKernelGGL(k_fused, dim3(GRID), dim3(256), 0, stream,
        (const float*)d_in[0], (const float*)d_in[1], (const float*)d_in[2],
        (const float*)d_in[3], (const float*)d_in[4], (const float*)d_in[5],
        (const float*)d_in[6], (float*)d_out, d_ws);
}